// Round 2
// baseline (786.756 us; speedup 1.0000x reference)
//
#include <hip/hip_runtime.h>
#include <cstdint>
#include <cstddef>

typedef __attribute__((ext_vector_type(4))) float    f32x4;
typedef __attribute__((ext_vector_type(8))) __bf16   bf16x8;
typedef __attribute__((ext_vector_type(4))) short    s16x4;
typedef __attribute__((ext_vector_type(4))) uint32_t u32x4;
typedef __attribute__((ext_vector_type(2))) uint32_t u32x2;

__device__ __forceinline__ float bf2f(uint16_t h) {
    uint32_t u = ((uint32_t)h) << 16;
    return __builtin_bit_cast(float, u);
}
__device__ __forceinline__ uint16_t f2bf(float f) {
    uint32_t u = __builtin_bit_cast(uint32_t, f);
    uint32_t r = (u + 0x7fffu + ((u >> 16) & 1u)) >> 16;  // RNE
    return (uint16_t)r;
}

__device__ __forceinline__ f32x4 mfma32(bf16x8 a, bf16x8 b, f32x4 c) {
    return __builtin_amdgcn_mfma_f32_16x16x32_bf16(a, b, c, 0, 0, 0);
}
__device__ __forceinline__ f32x4 mfma16(s16x4 a, s16x4 b, f32x4 c) {
    return __builtin_amdgcn_mfma_f32_16x16x16bf16_1k(a, b, c, 0, 0, 0);
}

// async global->LDS, 16B per lane. lds must be wave-uniform; lane i lands at lds + i*16.
__device__ __forceinline__ void gload16(const void* g, void* l) {
    __builtin_amdgcn_global_load_lds(
        (const __attribute__((address_space(1))) uint32_t*)g,
        (__attribute__((address_space(3))) uint32_t*)l, 16, 0, 0);
}

// ---------------------------------------------------------------------------
// fp32 -> bf16 elementwise, 4 elems/thread/iter, grid-stride
// ---------------------------------------------------------------------------
__global__ __launch_bounds__(256) void cvt_bf16(
    const float* __restrict__ s, uint16_t* __restrict__ d, int n4)
{
    int i = blockIdx.x * 256 + threadIdx.x;
    const int stride = gridDim.x * 256;
    for (; i < n4; i += stride) {
        f32x4 v = ((const f32x4*)s)[i];
        u32x2 p;
        p[0] = (uint32_t)f2bf(v[0]) | ((uint32_t)f2bf(v[1]) << 16);
        p[1] = (uint32_t)f2bf(v[2]) | ((uint32_t)f2bf(v[3]) << 16);
        ((u32x2*)d)[i] = p;
    }
}

// ---------------------------------------------------------------------------
// C[M,N] = A[M,K] @ B[N,K]^T, bf16 in, fp32 acc.
// F32OUT=false: C bf16.  F32OUT=true: C fp32 = acc + R (R fp32 residual).
// m97 structure: 128x128 tile, 4 waves (2x2 of 64x64), BK=32, global_load_lds w=16.
// ---------------------------------------------------------------------------
template <bool F32OUT>
__global__ __launch_bounds__(256) void gemm_bt(
    const uint16_t* __restrict__ A, const uint16_t* __restrict__ B,
    void* __restrict__ Cv, const float* __restrict__ R,
    int M, int N, int K)
{
    __shared__ __align__(16) uint16_t lA[128 * 32];
    __shared__ __align__(16) uint16_t lB[128 * 32];
    const int tid = threadIdx.x;
    const int wv = tid >> 6, ln = tid & 63;
    const int l15 = ln & 15, q = ln >> 4;
    const int m0 = blockIdx.y * 128, n0 = blockIdx.x * 128;
    const int wm = (wv >> 1) * 64, wn = (wv & 1) * 64;

    // staging: wave wv covers rows [wv*32, wv*32+32) in two 16-row wave-instrs
    const uint16_t* ga = A + (size_t)(m0 + wv * 32 + (ln >> 2)) * K + (ln & 3) * 8;
    const uint16_t* gb = B + (size_t)(n0 + wv * 32 + (ln >> 2)) * K + (ln & 3) * 8;
    uint16_t* la = lA + (wv * 32) * 32;   // wave-uniform
    uint16_t* lb = lB + (wv * 32) * 32;

    f32x4 acc[4][4];
    for (int i = 0; i < 4; i++)
        for (int j = 0; j < 4; j++)
            acc[i][j] = (f32x4){0.f, 0.f, 0.f, 0.f};

    for (int kt = 0; kt < K; kt += 32) {
        gload16(ga + kt, la);
        gload16(ga + (size_t)16 * K + kt, la + 16 * 32);
        gload16(gb + kt, lb);
        gload16(gb + (size_t)16 * K + kt, lb + 16 * 32);
        __syncthreads();

        bf16x8 af[4], bfv[4];
        for (int mt = 0; mt < 4; mt++)
            af[mt] = __builtin_bit_cast(bf16x8,
                *(const u32x4*)(lA + (wm + mt * 16 + l15) * 32 + q * 8));
        for (int nt = 0; nt < 4; nt++)
            bfv[nt] = __builtin_bit_cast(bf16x8,
                *(const u32x4*)(lB + (wn + nt * 16 + l15) * 32 + q * 8));
        for (int mt = 0; mt < 4; mt++)
            for (int nt = 0; nt < 4; nt++)
                acc[mt][nt] = mfma32(af[mt], bfv[nt], acc[mt][nt]);
        __syncthreads();
    }

    // epilogue: C/D layout row = q*4+r, col = l15
    for (int mt = 0; mt < 4; mt++)
        for (int nt = 0; nt < 4; nt++)
            for (int r = 0; r < 4; r++) {
                int row = m0 + wm + mt * 16 + q * 4 + r;
                int col = n0 + wn + nt * 16 + l15;
                size_t idx = (size_t)row * N + col;
                float v = acc[mt][nt][r];
                if (F32OUT) {
                    ((float*)Cv)[idx] = v + R[idx];
                } else {
                    ((uint16_t*)Cv)[idx] = f2bf(v);
                }
            }
}

// ---------------------------------------------------------------------------
// RoPE in-place on k buffer [8192 tok][2048] bf16, col = h*128 + d, pair (p, p+64)
// ---------------------------------------------------------------------------
__global__ __launch_bounds__(256) void rope_k(uint16_t* __restrict__ Kp)
{
    size_t i = (size_t)blockIdx.x * 256 + threadIdx.x;  // 8192*16*64
    int p = (int)(i & 63);
    size_t rest = i >> 6;
    int h = (int)(rest & 15);
    size_t tok = rest >> 4;
    int s = (int)(tok & 2047);
    uint16_t* base = Kp + tok * 2048 + (size_t)h * 128;
    float u1 = bf2f(base[p]), u2 = bf2f(base[p + 64]);
    float inv_freq = exp2f((float)p * (-13.287712379549449f / 64.0f)); // 10000^(-p/64)
    float a = (float)s * inv_freq;
    float sn, cs;
    sincosf(a, &sn, &cs);
    base[p]      = f2bf(u1 * cs - u2 * sn);
    base[p + 64] = f2bf(u2 * cs + u1 * sn);
}

// ---------------------------------------------------------------------------
// TTT scan: one wave per (b, h, e-block of 32 W-columns). 128 serial steps.
// W master fp32 in registers (16x16 C-layout tiles); bf16 shadow in LDS [e][d].
// pred = k@W (mfma 16x16x32); G = k k^T; errS = -(err)/1024;
// W += k^T @ errS (mfma 16x16x16, C-accumulate); out = pred + G @ errS.
// W0 is fp32; k/v/o are bf16.
// ---------------------------------------------------------------------------
__global__ __launch_bounds__(64) void ttt_scan(
    const uint16_t* __restrict__ Kp, const uint16_t* __restrict__ Vp,
    const float* __restrict__ W0, uint16_t* __restrict__ O)
{
    __shared__ __align__(16) uint16_t kbuf[16 * 136];   // [m][d], +8 bf16 row pad
    __shared__ __align__(16) uint16_t wb[32 * 136];     // [e][d] bf16 shadow of W

    const int g = blockIdx.x;
    const int eb = g & 3, h = (g >> 2) & 15, b = g >> 6;
    const int e0 = eb * 32;
    const int ln = threadIdx.x;
    const int l15 = ln & 15, q = ln >> 4;

    // W[mt][nt] reg r holds W[d = 16mt+4q+r][e = e0+16nt+l15]  (fp32 master)
    f32x4 W[8][2];
    {
        const float* w0p = W0 + (size_t)(b * 16 + h) * 128 * 128;
        for (int mt = 0; mt < 8; mt++)
            for (int nt = 0; nt < 2; nt++)
                for (int r = 0; r < 4; r++)
                    W[mt][nt][r] = w0p[(size_t)(16 * mt + 4 * q + r) * 128
                                       + e0 + 16 * nt + l15];
    }
    // initial bf16 shadow
    for (int mt = 0; mt < 8; mt++)
        for (int nt = 0; nt < 2; nt++) {
            uint32_t p0 = (uint32_t)f2bf(W[mt][nt][0]) | ((uint32_t)f2bf(W[mt][nt][1]) << 16);
            uint32_t p1 = (uint32_t)f2bf(W[mt][nt][2]) | ((uint32_t)f2bf(W[mt][nt][3]) << 16);
            int e = 16 * nt + l15, d = 16 * mt + 4 * q;
            *(uint32_t*)(wb + e * 136 + d)     = p0;
            *(uint32_t*)(wb + e * 136 + d + 2) = p1;
        }
    __syncthreads();

    const uint16_t* kbase = Kp + (size_t)b * 2048 * 2048 + h * 128;
    const uint16_t* vbase = Vp + (size_t)b * 2048 * 2048 + h * 128 + e0;
    uint16_t*       obase = O  + (size_t)b * 2048 * 2048 + h * 128 + e0;

    u32x4 kr[4];
    float vv[2][4];
    for (int i = 0; i < 4; i++)
        kr[i] = *(const u32x4*)(kbase + (size_t)(i * 4 + q) * 2048 + l15 * 8);
    for (int nt = 0; nt < 2; nt++)
        for (int r = 0; r < 4; r++)
            vv[nt][r] = bf2f(vbase[(size_t)(4 * q + r) * 2048 + 16 * nt + l15]);

    for (int c = 0; c < 128; c++) {
        const int s0 = c * 16;
        // stage k tile into LDS
        for (int i = 0; i < 4; i++)
            *(u32x4*)(kbuf + (i * 4 + q) * 136 + l15 * 8) = kr[i];
        __syncthreads();

        // prefetch next step's k/v while computing
        u32x4 krn[4];
        float vvn[2][4];
        if (c < 127) {
            const int s1 = s0 + 16;
            for (int i = 0; i < 4; i++)
                krn[i] = *(const u32x4*)(kbase + (size_t)(s1 + i * 4 + q) * 2048 + l15 * 8);
            for (int nt = 0; nt < 2; nt++)
                for (int r = 0; r < 4; r++)
                    vvn[nt][r] = bf2f(vbase[(size_t)(s1 + 4 * q + r) * 2048 + 16 * nt + l15]);
        }

        // A-frags: A[m=l15][d = ks*32 + q*8 + j]
        bf16x8 af[4];
        for (int ks = 0; ks < 4; ks++)
            af[ks] = __builtin_bit_cast(bf16x8,
                *(const u32x4*)(kbuf + l15 * 136 + ks * 32 + q * 8));

        // pred (2 n-tiles) and G = k k^T (B-frag == A-frag data)
        f32x4 acc0 = (f32x4){0.f, 0.f, 0.f, 0.f};
        f32x4 acc1 = (f32x4){0.f, 0.f, 0.f, 0.f};
        f32x4 gacc = (f32x4){0.f, 0.f, 0.f, 0.f};
        for (int ks = 0; ks < 4; ks++) {
            bf16x8 b0 = __builtin_bit_cast(bf16x8,
                *(const u32x4*)(wb + (l15) * 136 + ks * 32 + q * 8));
            bf16x8 b1 = __builtin_bit_cast(bf16x8,
                *(const u32x4*)(wb + (16 + l15) * 136 + ks * 32 + q * 8));
            acc0 = mfma32(af[ks], b0, acc0);
            acc1 = mfma32(af[ks], b1, acc1);
            gacc = mfma32(af[ks], af[ks], gacc);
        }

        // errS = -(pred - v)/1024, already in 16x16x16 A/B operand layout
        s16x4 es0, es1;
        for (int r = 0; r < 4; r++) {
            es0[r] = (short)f2bf(-(1.0f / 1024.0f) * (acc0[r] - vv[0][r]));
            es1[r] = (short)f2bf(-(1.0f / 1024.0f) * (acc1[r] - vv[1][r]));
        }
        // G is symmetric: C-layout regs serve as A-frag
        s16x4 gf;
        for (int r = 0; r < 4; r++) gf[r] = (short)f2bf(gacc[r]);

        // out = pred + G @ errS
        f32x4 o0 = mfma16(gf, es0, acc0);
        f32x4 o1 = mfma16(gf, es1, acc1);

        // W update: W += k^T @ errS  (A = k^T read as strided u16 from kbuf)
        for (int mt = 0; mt < 8; mt++) {
            s16x4 ktf;
            for (int j = 0; j < 4; j++)
                ktf[j] = (short)kbuf[(4 * q + j) * 136 + 16 * mt + l15];
            W[mt][0] = mfma16(ktf, es0, W[mt][0]);
            W[mt][1] = mfma16(ktf, es1, W[mt][1]);
        }
        __syncthreads();

        // refresh bf16 shadow for next step's pred
        for (int mt = 0; mt < 8; mt++)
            for (int nt = 0; nt < 2; nt++) {
                uint32_t p0 = (uint32_t)f2bf(W[mt][nt][0]) | ((uint32_t)f2bf(W[mt][nt][1]) << 16);
                uint32_t p1 = (uint32_t)f2bf(W[mt][nt][2]) | ((uint32_t)f2bf(W[mt][nt][3]) << 16);
                int e = 16 * nt + l15, d = 16 * mt + 4 * q;
                *(uint32_t*)(wb + e * 136 + d)     = p0;
                *(uint32_t*)(wb + e * 136 + d + 2) = p1;
            }

        // store out chunk
        for (int r = 0; r < 4; r++) {
            obase[(size_t)(s0 + 4 * q + r) * 2048 + l15]      = f2bf(o0[r]);
            obase[(size_t)(s0 + 4 * q + r) * 2048 + 16 + l15] = f2bf(o1[r]);
        }

        if (c < 127) {
            for (int i = 0; i < 4; i++) kr[i] = krn[i];
            for (int nt = 0; nt < 2; nt++)
                for (int r = 0; r < 4; r++) vv[nt][r] = vvn[nt][r];
        }
        __syncthreads();
    }
}

// ---------------------------------------------------------------------------
// LayerNorm over rows of 2048 (biased var), * g + b; X bf16, g/b fp32, Y bf16
// ---------------------------------------------------------------------------
__global__ __launch_bounds__(256) void ln_kernel(
    const uint16_t* __restrict__ X, const float* __restrict__ Gm,
    const float* __restrict__ Bt, uint16_t* __restrict__ Y)
{
    const int row = blockIdx.x, t = threadIdx.x;
    const uint16_t* xr = X + (size_t)row * 2048 + t * 8;
    u32x4 raw = *(const u32x4*)xr;
    const uint16_t* pr = (const uint16_t*)&raw;
    float v[8];
    float s = 0.f, s2 = 0.f;
    for (int i = 0; i < 8; i++) {
        v[i] = bf2f(pr[i]);
        s += v[i];
        s2 += v[i] * v[i];
    }
    for (int off = 32; off; off >>= 1) {
        s  += __shfl_down(s, off, 64);
        s2 += __shfl_down(s2, off, 64);
    }
    __shared__ float red[8];
    if ((t & 63) == 0) { red[(t >> 6) * 2] = s; red[(t >> 6) * 2 + 1] = s2; }
    __syncthreads();
    float ts  = red[0] + red[2] + red[4] + red[6];
    float ts2 = red[1] + red[3] + red[5] + red[7];
    float mu  = ts * (1.0f / 2048.0f);
    float var = ts2 * (1.0f / 2048.0f) - mu * mu;
    float inv = rsqrtf(var + 1e-5f);
    uint16_t outv[8];
    for (int i = 0; i < 8; i++) {
        float y = (v[i] - mu) * inv * Gm[t * 8 + i] + Bt[t * 8 + i];
        outv[i] = f2bf(y);
    }
    u32x4 ov;
    __builtin_memcpy(&ov, outv, 16);
    *(u32x4*)(Y + (size_t)row * 2048 + t * 8) = ov;
}

// ---------------------------------------------------------------------------
extern "C" void kernel_launch(void* const* d_in, const int* in_sizes, int n_in,
                              void* d_out, int out_size, void* d_ws, size_t ws_size,
                              hipStream_t stream)
{
    const float* x  = (const float*)d_in[0];
    const float* Wk = (const float*)d_in[1];
    const float* Wv = (const float*)d_in[2];
    const float* Wo = (const float*)d_in[3];
    const float* lg = (const float*)d_in[4];
    const float* lb = (const float*)d_in[5];
    const float* W0 = (const float*)d_in[6];
    float* out = (float*)d_out;

    const size_t NTOK = 8192, HID = 2048;
    // workspace layout (bf16 u16 elems): xb | wbuf | kb | vb  (= ~109 MB)
    uint16_t* xb   = (uint16_t*)d_ws;          // 8192*2048
    uint16_t* wbuf = xb + NTOK * HID;          // 2048*2048 (Wk, then Wv, then Wo)
    uint16_t* kb   = wbuf + HID * HID;         // 8192*2048
    uint16_t* vb   = kb + NTOK * HID;          // 8192*2048
    uint16_t* ob   = (uint16_t*)d_out;         // scan out parks in d_out bytes (dead
                                               // before final gemm overwrites, stream-ordered)
    uint16_t* lnb  = kb;                       // kb dead after scan

    dim3 grid(16, 64), blk(256);
    const int nX4 = (int)(NTOK * HID / 4), nW4 = (int)(HID * HID / 4);

    cvt_bf16<<<4096, 256, 0, stream>>>(x, xb, nX4);
    cvt_bf16<<<4096, 256, 0, stream>>>(Wk, wbuf, nW4);
    gemm_bt<false><<<grid, blk, 0, stream>>>(xb, wbuf, kb, nullptr, 8192, 2048, 2048);
    cvt_bf16<<<4096, 256, 0, stream>>>(Wv, wbuf, nW4);
    gemm_bt<false><<<grid, blk, 0, stream>>>(xb, wbuf, vb, nullptr, 8192, 2048, 2048);
    rope_k<<<32768, 256, 0, stream>>>(kb);
    ttt_scan<<<256, 64, 0, stream>>>(kb, vb, W0, ob);
    ln_kernel<<<8192, 256, 0, stream>>>(ob, lg, lb, lnb);
    cvt_bf16<<<4096, 256, 0, stream>>>(Wo, wbuf, nW4);
    gemm_bt<true><<<grid, blk, 0, stream>>>(lnb, wbuf, out, x, 8192, 2048, 2048);
}

// Round 3
// 746.261 us; speedup vs baseline: 1.0543x; 1.0543x over previous
//
#include <hip/hip_runtime.h>
#include <cstdint>
#include <cstddef>

typedef __attribute__((ext_vector_type(4))) float    f32x4;
typedef __attribute__((ext_vector_type(8))) __bf16   bf16x8;
typedef __attribute__((ext_vector_type(4))) short    s16x4;
typedef __attribute__((ext_vector_type(4))) uint32_t u32x4;
typedef __attribute__((ext_vector_type(2))) uint32_t u32x2;

__device__ __forceinline__ float bf2f(uint16_t h) {
    uint32_t u = ((uint32_t)h) << 16;
    return __builtin_bit_cast(float, u);
}
__device__ __forceinline__ uint16_t f2bf(float f) {
    uint32_t u = __builtin_bit_cast(uint32_t, f);
    uint32_t r = (u + 0x7fffu + ((u >> 16) & 1u)) >> 16;  // RNE
    return (uint16_t)r;
}
// native HW convert (v_cvt_pk_bf16_f32 on gfx950), RNE — for hot loops
__device__ __forceinline__ uint16_t f2bf_fast(float f) {
    __bf16 h = (__bf16)f;
    return __builtin_bit_cast(uint16_t, h);
}

__device__ __forceinline__ f32x4 mfma32(bf16x8 a, bf16x8 b, f32x4 c) {
    return __builtin_amdgcn_mfma_f32_16x16x32_bf16(a, b, c, 0, 0, 0);
}
__device__ __forceinline__ f32x4 mfma16(s16x4 a, s16x4 b, f32x4 c) {
    return __builtin_amdgcn_mfma_f32_16x16x16bf16_1k(a, b, c, 0, 0, 0);
}

// async global->LDS, 16B per lane. lds must be wave-uniform; lane i lands at lds + i*16.
__device__ __forceinline__ void gload16(const void* g, void* l) {
    __builtin_amdgcn_global_load_lds(
        (const __attribute__((address_space(1))) uint32_t*)g,
        (__attribute__((address_space(3))) uint32_t*)l, 16, 0, 0);
}

// ---------------------------------------------------------------------------
// fp32 -> bf16 elementwise, 4 elems/thread/iter, grid-stride
// ---------------------------------------------------------------------------
__global__ __launch_bounds__(256) void cvt_bf16(
    const float* __restrict__ s, uint16_t* __restrict__ d, int n4)
{
    int i = blockIdx.x * 256 + threadIdx.x;
    const int stride = gridDim.x * 256;
    for (; i < n4; i += stride) {
        f32x4 v = ((const f32x4*)s)[i];
        u32x2 p;
        p[0] = (uint32_t)f2bf(v[0]) | ((uint32_t)f2bf(v[1]) << 16);
        p[1] = (uint32_t)f2bf(v[2]) | ((uint32_t)f2bf(v[3]) << 16);
        ((u32x2*)d)[i] = p;
    }
}

// ---------------------------------------------------------------------------
// C[M,N] = A[M,K] @ B[N,K]^T, bf16 in, fp32 acc.
// F32OUT=false: C bf16.  F32OUT=true: C fp32 = acc + R (R fp32 residual).
// m97 structure: 128x128 tile, 4 waves (2x2 of 64x64), BK=32, global_load_lds w=16.
// ---------------------------------------------------------------------------
template <bool F32OUT>
__global__ __launch_bounds__(256) void gemm_bt(
    const uint16_t* __restrict__ A, const uint16_t* __restrict__ B,
    void* __restrict__ Cv, const float* __restrict__ R,
    int M, int N, int K)
{
    __shared__ __align__(16) uint16_t lA[128 * 32];
    __shared__ __align__(16) uint16_t lB[128 * 32];
    const int tid = threadIdx.x;
    const int wv = tid >> 6, ln = tid & 63;
    const int l15 = ln & 15, q = ln >> 4;
    const int m0 = blockIdx.y * 128, n0 = blockIdx.x * 128;
    const int wm = (wv >> 1) * 64, wn = (wv & 1) * 64;

    // staging: wave wv covers rows [wv*32, wv*32+32) in two 16-row wave-instrs
    const uint16_t* ga = A + (size_t)(m0 + wv * 32 + (ln >> 2)) * K + (ln & 3) * 8;
    const uint16_t* gb = B + (size_t)(n0 + wv * 32 + (ln >> 2)) * K + (ln & 3) * 8;
    uint16_t* la = lA + (wv * 32) * 32;   // wave-uniform
    uint16_t* lb = lB + (wv * 32) * 32;

    f32x4 acc[4][4];
    for (int i = 0; i < 4; i++)
        for (int j = 0; j < 4; j++)
            acc[i][j] = (f32x4){0.f, 0.f, 0.f, 0.f};

    for (int kt = 0; kt < K; kt += 32) {
        gload16(ga + kt, la);
        gload16(ga + (size_t)16 * K + kt, la + 16 * 32);
        gload16(gb + kt, lb);
        gload16(gb + (size_t)16 * K + kt, lb + 16 * 32);
        __syncthreads();

        bf16x8 af[4], bfv[4];
        for (int mt = 0; mt < 4; mt++)
            af[mt] = __builtin_bit_cast(bf16x8,
                *(const u32x4*)(lA + (wm + mt * 16 + l15) * 32 + q * 8));
        for (int nt = 0; nt < 4; nt++)
            bfv[nt] = __builtin_bit_cast(bf16x8,
                *(const u32x4*)(lB + (wn + nt * 16 + l15) * 32 + q * 8));
        for (int mt = 0; mt < 4; mt++)
            for (int nt = 0; nt < 4; nt++)
                acc[mt][nt] = mfma32(af[mt], bfv[nt], acc[mt][nt]);
        __syncthreads();
    }

    // epilogue: C/D layout row = q*4+r, col = l15
    for (int mt = 0; mt < 4; mt++)
        for (int nt = 0; nt < 4; nt++)
            for (int r = 0; r < 4; r++) {
                int row = m0 + wm + mt * 16 + q * 4 + r;
                int col = n0 + wn + nt * 16 + l15;
                size_t idx = (size_t)row * N + col;
                float v = acc[mt][nt][r];
                if (F32OUT) {
                    ((float*)Cv)[idx] = v + R[idx];
                } else {
                    ((uint16_t*)Cv)[idx] = f2bf(v);
                }
            }
}

// ---------------------------------------------------------------------------
// RoPE in-place on k buffer [8192 tok][2048] bf16, col = h*128 + d, pair (p, p+64)
// ---------------------------------------------------------------------------
__global__ __launch_bounds__(256) void rope_k(uint16_t* __restrict__ Kp)
{
    size_t i = (size_t)blockIdx.x * 256 + threadIdx.x;  // 8192*16*64
    int p = (int)(i & 63);
    size_t rest = i >> 6;
    int h = (int)(rest & 15);
    size_t tok = rest >> 4;
    int s = (int)(tok & 2047);
    uint16_t* base = Kp + tok * 2048 + (size_t)h * 128;
    float u1 = bf2f(base[p]), u2 = bf2f(base[p + 64]);
    float inv_freq = exp2f((float)p * (-13.287712379549449f / 64.0f)); // 10000^(-p/64)
    float a = (float)s * inv_freq;
    float sn, cs;
    sincosf(a, &sn, &cs);
    base[p]      = f2bf(u1 * cs - u2 * sn);
    base[p + 64] = f2bf(u2 * cs + u1 * sn);
}

// ---------------------------------------------------------------------------
// TTT scan: one wave per (b, h, e-block of 32 W-columns). 128 serial steps.
// Single-wave workgroup => NO __syncthreads. Per-wave LDS ops execute in order
// at the LDS; __builtin_amdgcn_wave_barrier() (zero-cost compiler fence) pins
// instruction order at the cross-lane-alias points. kbuf double-buffered so
// next-iter staging never aliases current-iter reads.
// W master fp32 in registers (16x16 C-layout tiles); bf16 shadow in LDS [e][d].
// pred = k@W (mfma 16x16x32); G = k k^T; errS = -(err)/1024;
// W += k^T @ errS (mfma 16x16x16, C-accumulate); out = pred + G @ errS.
// ---------------------------------------------------------------------------
__global__ __launch_bounds__(64) void ttt_scan(
    const uint16_t* __restrict__ Kp, const uint16_t* __restrict__ Vp,
    const float* __restrict__ W0, uint16_t* __restrict__ O)
{
    __shared__ __align__(16) uint16_t kbuf[2][16 * 136];  // [m][d], +8 bf16 row pad
    __shared__ __align__(16) uint16_t wb[32 * 136];       // [e][d] bf16 shadow of W

    const int g = blockIdx.x;
    const int eb = g & 3, h = (g >> 2) & 15, b = g >> 6;
    const int e0 = eb * 32;
    const int ln = threadIdx.x;
    const int l15 = ln & 15, q = ln >> 4;

    // W[mt][nt] reg r holds W[d = 16mt+4q+r][e = e0+16nt+l15]  (fp32 master)
    f32x4 W[8][2];
    {
        const float* w0p = W0 + (size_t)(b * 16 + h) * 128 * 128;
        for (int mt = 0; mt < 8; mt++)
            for (int nt = 0; nt < 2; nt++)
                for (int r = 0; r < 4; r++)
                    W[mt][nt][r] = w0p[(size_t)(16 * mt + 4 * q + r) * 128
                                       + e0 + 16 * nt + l15];
    }
    // initial bf16 shadow
    for (int mt = 0; mt < 8; mt++)
        for (int nt = 0; nt < 2; nt++) {
            uint32_t p0 = (uint32_t)f2bf_fast(W[mt][nt][0]) | ((uint32_t)f2bf_fast(W[mt][nt][1]) << 16);
            uint32_t p1 = (uint32_t)f2bf_fast(W[mt][nt][2]) | ((uint32_t)f2bf_fast(W[mt][nt][3]) << 16);
            int e = 16 * nt + l15, d = 16 * mt + 4 * q;
            *(uint32_t*)(wb + e * 136 + d)     = p0;
            *(uint32_t*)(wb + e * 136 + d + 2) = p1;
        }
    __builtin_amdgcn_wave_barrier();   // wb init before loop's wb reads

    const uint16_t* kbase = Kp + (size_t)b * 2048 * 2048 + h * 128;
    const uint16_t* vbase = Vp + (size_t)b * 2048 * 2048 + h * 128 + e0;
    uint16_t*       obase = O  + (size_t)b * 2048 * 2048 + h * 128 + e0;

    u32x4 kr[4];
    float vv[2][4];
    for (int i = 0; i < 4; i++)
        kr[i] = *(const u32x4*)(kbase + (size_t)(i * 4 + q) * 2048 + l15 * 8);
    for (int nt = 0; nt < 2; nt++)
        for (int r = 0; r < 4; r++)
            vv[nt][r] = bf2f(vbase[(size_t)(4 * q + r) * 2048 + 16 * nt + l15]);

    for (int c = 0; c < 128; c++) {
        const int s0 = c * 16;
        uint16_t* kb = kbuf[c & 1];

        // stage k tile into LDS (double-buffered)
        for (int i = 0; i < 4; i++)
            *(u32x4*)(kb + (i * 4 + q) * 136 + l15 * 8) = kr[i];
        __builtin_amdgcn_wave_barrier();   // staging before fragment reads

        // prefetch next step's k/v immediately: full-body latency window
        u32x4 krn[4];
        float vvn[2][4];
        if (c < 127) {
            const int s1 = s0 + 16;
            for (int i = 0; i < 4; i++)
                krn[i] = *(const u32x4*)(kbase + (size_t)(s1 + i * 4 + q) * 2048 + l15 * 8);
            for (int nt = 0; nt < 2; nt++)
                for (int r = 0; r < 4; r++)
                    vvn[nt][r] = bf2f(vbase[(size_t)(s1 + 4 * q + r) * 2048 + 16 * nt + l15]);
        }

        // k^T fragments for the W update (issued early; independent of es)
        s16x4 ktf[8];
        for (int mt = 0; mt < 8; mt++)
            for (int j = 0; j < 4; j++)
                ktf[mt][j] = (short)kb[(4 * q + j) * 136 + 16 * mt + l15];

        // A-frags: A[m=l15][d = ks*32 + q*8 + j]
        bf16x8 af[4];
        for (int ks = 0; ks < 4; ks++)
            af[ks] = __builtin_bit_cast(bf16x8,
                *(const u32x4*)(kb + l15 * 136 + ks * 32 + q * 8));

        // pred (2 n-tiles) and G = k k^T (B-frag == A-frag data)
        f32x4 acc0 = (f32x4){0.f, 0.f, 0.f, 0.f};
        f32x4 acc1 = (f32x4){0.f, 0.f, 0.f, 0.f};
        f32x4 gacc = (f32x4){0.f, 0.f, 0.f, 0.f};
        for (int ks = 0; ks < 4; ks++) {
            bf16x8 b0 = __builtin_bit_cast(bf16x8,
                *(const u32x4*)(wb + (l15) * 136 + ks * 32 + q * 8));
            bf16x8 b1 = __builtin_bit_cast(bf16x8,
                *(const u32x4*)(wb + (16 + l15) * 136 + ks * 32 + q * 8));
            acc0 = mfma32(af[ks], b0, acc0);
            acc1 = mfma32(af[ks], b1, acc1);
            gacc = mfma32(af[ks], af[ks], gacc);
        }

        // errS = -(pred - v)/1024, already in 16x16x16 A/B operand layout
        s16x4 es0, es1;
        for (int r = 0; r < 4; r++) {
            es0[r] = (short)f2bf_fast(-(1.0f / 1024.0f) * (acc0[r] - vv[0][r]));
            es1[r] = (short)f2bf_fast(-(1.0f / 1024.0f) * (acc1[r] - vv[1][r]));
        }
        // G is symmetric: C-layout regs serve as A-frag
        s16x4 gf;
        for (int r = 0; r < 4; r++) gf[r] = (short)f2bf_fast(gacc[r]);

        // out = pred + G @ errS
        f32x4 o0 = mfma16(gf, es0, acc0);
        f32x4 o1 = mfma16(gf, es1, acc1);

        // W update: W += k^T @ errS
        for (int mt = 0; mt < 8; mt++) {
            W[mt][0] = mfma16(ktf[mt], es0, W[mt][0]);
            W[mt][1] = mfma16(ktf[mt], es1, W[mt][1]);
        }

        // store out chunk (fire-and-forget)
        for (int r = 0; r < 4; r++) {
            obase[(size_t)(s0 + 4 * q + r) * 2048 + l15]      = f2bf_fast(o0[r]);
            obase[(size_t)(s0 + 4 * q + r) * 2048 + 16 + l15] = f2bf_fast(o1[r]);
        }

        __builtin_amdgcn_wave_barrier();   // this iter's wb reads before writes
        // refresh bf16 shadow for next step's pred
        for (int mt = 0; mt < 8; mt++)
            for (int nt = 0; nt < 2; nt++) {
                uint32_t p0 = (uint32_t)f2bf_fast(W[mt][nt][0]) | ((uint32_t)f2bf_fast(W[mt][nt][1]) << 16);
                uint32_t p1 = (uint32_t)f2bf_fast(W[mt][nt][2]) | ((uint32_t)f2bf_fast(W[mt][nt][3]) << 16);
                int e = 16 * nt + l15, d = 16 * mt + 4 * q;
                *(uint32_t*)(wb + e * 136 + d)     = p0;
                *(uint32_t*)(wb + e * 136 + d + 2) = p1;
            }
        __builtin_amdgcn_wave_barrier();   // wb writes before next iter's reads

        if (c < 127) {
            for (int i = 0; i < 4; i++) kr[i] = krn[i];
            for (int nt = 0; nt < 2; nt++)
                for (int r = 0; r < 4; r++) vv[nt][r] = vvn[nt][r];
        }
    }
}

// ---------------------------------------------------------------------------
// LayerNorm over rows of 2048 (biased var), * g + b; X bf16, g/b fp32, Y bf16
// ---------------------------------------------------------------------------
__global__ __launch_bounds__(256) void ln_kernel(
    const uint16_t* __restrict__ X, const float* __restrict__ Gm,
    const float* __restrict__ Bt, uint16_t* __restrict__ Y)
{
    const int row = blockIdx.x, t = threadIdx.x;
    const uint16_t* xr = X + (size_t)row * 2048 + t * 8;
    u32x4 raw = *(const u32x4*)xr;
    const uint16_t* pr = (const uint16_t*)&raw;
    float v[8];
    float s = 0.f, s2 = 0.f;
    for (int i = 0; i < 8; i++) {
        v[i] = bf2f(pr[i]);
        s += v[i];
        s2 += v[i] * v[i];
    }
    for (int off = 32; off; off >>= 1) {
        s  += __shfl_down(s, off, 64);
        s2 += __shfl_down(s2, off, 64);
    }
    __shared__ float red[8];
    if ((t & 63) == 0) { red[(t >> 6) * 2] = s; red[(t >> 6) * 2 + 1] = s2; }
    __syncthreads();
    float ts  = red[0] + red[2] + red[4] + red[6];
    float ts2 = red[1] + red[3] + red[5] + red[7];
    float mu  = ts * (1.0f / 2048.0f);
    float var = ts2 * (1.0f / 2048.0f) - mu * mu;
    float inv = rsqrtf(var + 1e-5f);
    uint16_t outv[8];
    for (int i = 0; i < 8; i++) {
        float y = (v[i] - mu) * inv * Gm[t * 8 + i] + Bt[t * 8 + i];
        outv[i] = f2bf(y);
    }
    u32x4 ov;
    __builtin_memcpy(&ov, outv, 16);
    *(u32x4*)(Y + (size_t)row * 2048 + t * 8) = ov;
}

// ---------------------------------------------------------------------------
extern "C" void kernel_launch(void* const* d_in, const int* in_sizes, int n_in,
                              void* d_out, int out_size, void* d_ws, size_t ws_size,
                              hipStream_t stream)
{
    const float* x  = (const float*)d_in[0];
    const float* Wk = (const float*)d_in[1];
    const float* Wv = (const float*)d_in[2];
    const float* Wo = (const float*)d_in[3];
    const float* lg = (const float*)d_in[4];
    const float* lb = (const float*)d_in[5];
    const float* W0 = (const float*)d_in[6];
    float* out = (float*)d_out;

    const size_t NTOK = 8192, HID = 2048;
    // workspace layout (bf16 u16 elems): xb | wbuf | kb | vb  (= ~109 MB)
    uint16_t* xb   = (uint16_t*)d_ws;          // 8192*2048
    uint16_t* wbuf = xb + NTOK * HID;          // 2048*2048 (Wk, then Wv, then Wo)
    uint16_t* kb   = wbuf + HID * HID;         // 8192*2048
    uint16_t* vb   = kb + NTOK * HID;          // 8192*2048
    uint16_t* ob   = (uint16_t*)d_out;         // scan out parks in d_out bytes (dead
                                               // before final gemm overwrites, stream-ordered)
    uint16_t* lnb  = kb;                       // kb dead after scan

    dim3 grid(16, 64), blk(256);
    const int nX4 = (int)(NTOK * HID / 4), nW4 = (int)(HID * HID / 4);

    cvt_bf16<<<4096, 256, 0, stream>>>(x, xb, nX4);
    cvt_bf16<<<4096, 256, 0, stream>>>(Wk, wbuf, nW4);
    gemm_bt<false><<<grid, blk, 0, stream>>>(xb, wbuf, kb, nullptr, 8192, 2048, 2048);
    cvt_bf16<<<4096, 256, 0, stream>>>(Wv, wbuf, nW4);
    gemm_bt<false><<<grid, blk, 0, stream>>>(xb, wbuf, vb, nullptr, 8192, 2048, 2048);
    rope_k<<<32768, 256, 0, stream>>>(kb);
    ttt_scan<<<256, 64, 0, stream>>>(kb, vb, W0, ob);
    ln_kernel<<<8192, 256, 0, stream>>>(ob, lg, lb, lnb);
    cvt_bf16<<<4096, 256, 0, stream>>>(Wo, wbuf, nW4);
    gemm_bt<true><<<grid, blk, 0, stream>>>(lnb, wbuf, out, x, 8192, 2048, 2048);
}

// Round 4
// 744.808 us; speedup vs baseline: 1.0563x; 1.0020x over previous
//
#include <hip/hip_runtime.h>
#include <cstdint>
#include <cstddef>

typedef __attribute__((ext_vector_type(4))) float    f32x4;
typedef __attribute__((ext_vector_type(8))) __bf16   bf16x8;
typedef __attribute__((ext_vector_type(4))) short    s16x4;
typedef __attribute__((ext_vector_type(4))) uint32_t u32x4;
typedef __attribute__((ext_vector_type(2))) uint32_t u32x2;

__device__ __forceinline__ float bf2f(uint16_t h) {
    uint32_t u = ((uint32_t)h) << 16;
    return __builtin_bit_cast(float, u);
}
__device__ __forceinline__ uint16_t f2bf(float f) {
    uint32_t u = __builtin_bit_cast(uint32_t, f);
    uint32_t r = (u + 0x7fffu + ((u >> 16) & 1u)) >> 16;  // RNE
    return (uint16_t)r;
}
// native HW convert (v_cvt_pk_bf16_f32 on gfx950), RNE — for hot loops
__device__ __forceinline__ uint16_t f2bf_fast(float f) {
    __bf16 h = (__bf16)f;
    return __builtin_bit_cast(uint16_t, h);
}

__device__ __forceinline__ f32x4 mfma32(bf16x8 a, bf16x8 b, f32x4 c) {
    return __builtin_amdgcn_mfma_f32_16x16x32_bf16(a, b, c, 0, 0, 0);
}
__device__ __forceinline__ f32x4 mfma16(s16x4 a, s16x4 b, f32x4 c) {
    return __builtin_amdgcn_mfma_f32_16x16x16bf16_1k(a, b, c, 0, 0, 0);
}

// async global->LDS, 16B per lane (GEMM staging)
__device__ __forceinline__ void gload16(const void* g, void* l) {
    __builtin_amdgcn_global_load_lds(
        (const __attribute__((address_space(1))) uint32_t*)g,
        (__attribute__((address_space(3))) uint32_t*)l, 16, 0, 0);
}

// ---------------------------------------------------------------------------
// fp32 -> bf16 elementwise, 4 elems/thread/iter, grid-stride
// ---------------------------------------------------------------------------
__global__ __launch_bounds__(256) void cvt_bf16(
    const float* __restrict__ s, uint16_t* __restrict__ d, int n4)
{
    int i = blockIdx.x * 256 + threadIdx.x;
    const int stride = gridDim.x * 256;
    for (; i < n4; i += stride) {
        f32x4 v = ((const f32x4*)s)[i];
        u32x2 p;
        p[0] = (uint32_t)f2bf(v[0]) | ((uint32_t)f2bf(v[1]) << 16);
        p[1] = (uint32_t)f2bf(v[2]) | ((uint32_t)f2bf(v[3]) << 16);
        ((u32x2*)d)[i] = p;
    }
}

// ---------------------------------------------------------------------------
// C[M,N] = A[M,K] @ B[N,K]^T, bf16 in, fp32 acc.  (m97 structure)
// ---------------------------------------------------------------------------
template <bool F32OUT>
__global__ __launch_bounds__(256) void gemm_bt(
    const uint16_t* __restrict__ A, const uint16_t* __restrict__ B,
    void* __restrict__ Cv, const float* __restrict__ R,
    int M, int N, int K)
{
    __shared__ __align__(16) uint16_t lA[128 * 32];
    __shared__ __align__(16) uint16_t lB[128 * 32];
    const int tid = threadIdx.x;
    const int wv = tid >> 6, ln = tid & 63;
    const int l15 = ln & 15, q = ln >> 4;
    const int m0 = blockIdx.y * 128, n0 = blockIdx.x * 128;
    const int wm = (wv >> 1) * 64, wn = (wv & 1) * 64;

    const uint16_t* ga = A + (size_t)(m0 + wv * 32 + (ln >> 2)) * K + (ln & 3) * 8;
    const uint16_t* gb = B + (size_t)(n0 + wv * 32 + (ln >> 2)) * K + (ln & 3) * 8;
    uint16_t* la = lA + (wv * 32) * 32;
    uint16_t* lb = lB + (wv * 32) * 32;

    f32x4 acc[4][4];
    for (int i = 0; i < 4; i++)
        for (int j = 0; j < 4; j++)
            acc[i][j] = (f32x4){0.f, 0.f, 0.f, 0.f};

    for (int kt = 0; kt < K; kt += 32) {
        gload16(ga + kt, la);
        gload16(ga + (size_t)16 * K + kt, la + 16 * 32);
        gload16(gb + kt, lb);
        gload16(gb + (size_t)16 * K + kt, lb + 16 * 32);
        __syncthreads();

        bf16x8 af[4], bfv[4];
        for (int mt = 0; mt < 4; mt++)
            af[mt] = __builtin_bit_cast(bf16x8,
                *(const u32x4*)(lA + (wm + mt * 16 + l15) * 32 + q * 8));
        for (int nt = 0; nt < 4; nt++)
            bfv[nt] = __builtin_bit_cast(bf16x8,
                *(const u32x4*)(lB + (wn + nt * 16 + l15) * 32 + q * 8));
        for (int mt = 0; mt < 4; mt++)
            for (int nt = 0; nt < 4; nt++)
                acc[mt][nt] = mfma32(af[mt], bfv[nt], acc[mt][nt]);
        __syncthreads();
    }

    for (int mt = 0; mt < 4; mt++)
        for (int nt = 0; nt < 4; nt++)
            for (int r = 0; r < 4; r++) {
                int row = m0 + wm + mt * 16 + q * 4 + r;
                int col = n0 + wn + nt * 16 + l15;
                size_t idx = (size_t)row * N + col;
                float v = acc[mt][nt][r];
                if (F32OUT) {
                    ((float*)Cv)[idx] = v + R[idx];
                } else {
                    ((uint16_t*)Cv)[idx] = f2bf(v);
                }
            }
}

// ---------------------------------------------------------------------------
// repack + fused RoPE: per (b,h,c) emit contiguous tiles
//   kp[g][m16][d128]  (roped k, [token][dim])
//   kt[g][d128][m16]  (roped k transposed)
//   vt[g][e128][m16]  (v transposed)
// g = ((b*16)+h)*128 + c.  64 threads/block, 8192 blocks.
// lane: m = ln>>2 (token in chunk), cb = (ln&3)*32 (col block)
// ---------------------------------------------------------------------------
__global__ __launch_bounds__(64) void repack(
    const uint16_t* __restrict__ kb, const uint16_t* __restrict__ vb,
    uint16_t* __restrict__ kp, uint16_t* __restrict__ kt,
    uint16_t* __restrict__ vt)
{
    const int g = blockIdx.x;
    const int c = g & 127, h = (g >> 7) & 15, b = g >> 11;
    const int ln = threadIdx.x;
    const int m = ln >> 2, cb = (ln & 3) * 32;
    const size_t tok = (size_t)b * 2048 + c * 16 + m;
    const int s = c * 16 + m;
    const uint16_t* krow = kb + tok * 2048 + h * 128;
    const uint16_t* vrow = vb + tok * 2048 + h * 128;

    u32x4 kraw[4], praw[4], vraw[4];
    for (int i = 0; i < 4; i++) {
        kraw[i] = *(const u32x4*)(krow + cb + 8 * i);
        praw[i] = *(const u32x4*)(krow + (cb ^ 64) + 8 * i);
        vraw[i] = *(const u32x4*)(vrow + cb + 8 * i);
    }
    const uint16_t* ku = (const uint16_t*)kraw;
    const uint16_t* pu = (const uint16_t*)praw;
    const uint16_t* vu = (const uint16_t*)vraw;

    uint16_t ko[32];
    for (int j = 0; j < 32; j++) {
        int col = cb + j;
        int p = col & 63;
        float invf = exp2f((float)p * (-13.287712379549449f / 64.0f));
        float a = (float)s * invf;
        float sn, cs;
        __sincosf(a, &sn, &cs);
        float u1 = bf2f(ku[j]), u2 = bf2f(pu[j]);
        float o = (col < 64) ? (u1 * cs - u2 * sn) : (u1 * cs + u2 * sn);
        ko[j] = f2bf(o);
    }

    uint16_t* kpg = kp + (size_t)g * 2048;
    uint16_t* ktg = kt + (size_t)g * 2048;
    uint16_t* vtg = vt + (size_t)g * 2048;
    // kp: vectorized [m][d]
    for (int i = 0; i < 4; i++) {
        u32x4 pk;
        uint32_t* pw = (uint32_t*)&pk;
        for (int w = 0; w < 4; w++)
            pw[w] = (uint32_t)ko[8 * i + 2 * w] | ((uint32_t)ko[8 * i + 2 * w + 1] << 16);
        *(u32x4*)(kpg + m * 128 + cb + 8 * i) = pk;
    }
    // kt / vt: scalar transposed stores (parallel kernel; latency hidden by 8192 blocks)
    for (int j = 0; j < 32; j++) {
        ktg[(cb + j) * 16 + m] = ko[j];
        vtg[(cb + j) * 16 + m] = vu[j];
    }
}

// ---------------------------------------------------------------------------
// TTT scan: one wave per (b, h, e-block of 32 W-columns). 128 serial steps.
// Contiguous repacked tiles, register prefetch depth 2, all-vector LDS.
// W master fp32 in registers (16x16 C-layout tiles); bf16 shadow in LDS [e][d].
// pred = k@W (mfma 16x16x32); G = k k^T; errS = (v-pred)/1024;
// W += k^T @ errS (mfma 16x16x16, C-accumulate); out = pred + G @ errS.
// ---------------------------------------------------------------------------
__global__ __launch_bounds__(64) void ttt_scan(
    const uint16_t* __restrict__ kp, const uint16_t* __restrict__ kt,
    const uint16_t* __restrict__ vt, const float* __restrict__ W0,
    uint16_t* __restrict__ O)
{
    __shared__ __align__(16) uint16_t kbuf[16 * 136];  // [m][d] +8 pad
    __shared__ __align__(16) uint16_t ktb[128 * 24];   // [d][m] +8 pad
    __shared__ __align__(16) uint16_t vtb[32 * 24];    // [e][m] +8 pad
    __shared__ __align__(16) uint16_t wb[32 * 136];    // [e][d] +8 pad

    const int g = blockIdx.x;
    const int eb = g & 3, h = (g >> 2) & 15, b = g >> 6;
    const int e0 = eb * 32;
    const int ln = threadIdx.x;
    const int l15 = ln & 15, q = ln >> 4;

    // W[mt][nt] reg r holds W[d = 16mt+4q+r][e = e0+16nt+l15]  (fp32 master)
    f32x4 W[8][2];
    {
        const float* w0p = W0 + (size_t)(b * 16 + h) * 128 * 128;
        for (int mt = 0; mt < 8; mt++)
            for (int nt = 0; nt < 2; nt++)
                for (int r = 0; r < 4; r++)
                    W[mt][nt][r] = w0p[(size_t)(16 * mt + 4 * q + r) * 128
                                       + e0 + 16 * nt + l15];
    }
    for (int mt = 0; mt < 8; mt++)
        for (int nt = 0; nt < 2; nt++) {
            uint32_t p0 = (uint32_t)f2bf_fast(W[mt][nt][0]) | ((uint32_t)f2bf_fast(W[mt][nt][1]) << 16);
            uint32_t p1 = (uint32_t)f2bf_fast(W[mt][nt][2]) | ((uint32_t)f2bf_fast(W[mt][nt][3]) << 16);
            int e = 16 * nt + l15, d = 16 * mt + 4 * q;
            *(uint32_t*)(wb + e * 136 + d)     = p0;
            *(uint32_t*)(wb + e * 136 + d + 2) = p1;
        }
    __builtin_amdgcn_wave_barrier();

    const uint16_t* kpw = kp + (size_t)(b * 16 + h) * 128 * 2048;
    const uint16_t* ktw = kt + (size_t)(b * 16 + h) * 128 * 2048;
    const uint16_t* vtw = vt + (size_t)(b * 16 + h) * 128 * 2048 + e0 * 16;
    uint16_t*     obase = O  + (size_t)b * 2048 * 2048 + h * 128 + e0;

    // prefetch buffers: [slot][0..3]=kp, [4..7]=kt, [8]=vt slice
    u32x4 buf[2][9];
    auto load_step = [&](int c, int slot) {
        const uint16_t* kpt = kpw + (size_t)c * 2048;
        const uint16_t* ktt = ktw + (size_t)c * 2048;
        const uint16_t* vtt = vtw + (size_t)c * 2048;
        for (int i = 0; i < 4; i++)
            buf[slot][i] = *(const u32x4*)(kpt + i * 512 + ln * 8);
        for (int i = 0; i < 4; i++)
            buf[slot][4 + i] = *(const u32x4*)(ktt + i * 512 + ln * 8);
        buf[slot][8] = *(const u32x4*)(vtt + ln * 8);
    };
    load_step(0, 0);
    load_step(1, 1);

    for (int c = 0; c < 128; c++) {
        const int s0 = c * 16;
        const int slot = c & 1;

        // stage tiles into padded LDS (all <=2-way banks)
        for (int i = 0; i < 4; i++)
            *(u32x4*)(kbuf + (i * 4 + (ln >> 4)) * 136 + (ln & 15) * 8) = buf[slot][i];
        for (int i = 0; i < 4; i++)
            *(u32x4*)(ktb + (i * 32 + (ln >> 1)) * 24 + (ln & 1) * 8) = buf[slot][4 + i];
        *(u32x4*)(vtb + (ln >> 1) * 24 + (ln & 1) * 8) = buf[slot][8];
        __builtin_amdgcn_wave_barrier();

        // refill this slot for step c+2 (regs free after staging issues)
        if (c < 126) load_step(c + 2, slot);

        // fragments
        bf16x8 af[4];
        for (int ks = 0; ks < 4; ks++)
            af[ks] = __builtin_bit_cast(bf16x8,
                *(const u32x4*)(kbuf + l15 * 136 + ks * 32 + q * 8));
        s16x4 ktf[8];
        for (int mt = 0; mt < 8; mt++)
            ktf[mt] = *(const s16x4*)(ktb + (16 * mt + l15) * 24 + 4 * q);
        s16x4 vv0 = *(const s16x4*)(vtb + l15 * 24 + 4 * q);
        s16x4 vv1 = *(const s16x4*)(vtb + (16 + l15) * 24 + 4 * q);

        // pred (2 n-tiles) and G = k k^T
        f32x4 acc0 = (f32x4){0.f, 0.f, 0.f, 0.f};
        f32x4 acc1 = (f32x4){0.f, 0.f, 0.f, 0.f};
        f32x4 gacc = (f32x4){0.f, 0.f, 0.f, 0.f};
        for (int ks = 0; ks < 4; ks++) {
            bf16x8 b0 = __builtin_bit_cast(bf16x8,
                *(const u32x4*)(wb + (l15) * 136 + ks * 32 + q * 8));
            bf16x8 b1 = __builtin_bit_cast(bf16x8,
                *(const u32x4*)(wb + (16 + l15) * 136 + ks * 32 + q * 8));
            acc0 = mfma32(af[ks], b0, acc0);
            acc1 = mfma32(af[ks], b1, acc1);
            gacc = mfma32(af[ks], af[ks], gacc);
        }

        // errS = (v - pred)/1024, already in 16x16x16 A/B operand layout
        s16x4 es0, es1;
        for (int r = 0; r < 4; r++) {
            es0[r] = (short)f2bf_fast((bf2f((uint16_t)vv0[r]) - acc0[r]) * (1.0f / 1024.0f));
            es1[r] = (short)f2bf_fast((bf2f((uint16_t)vv1[r]) - acc1[r]) * (1.0f / 1024.0f));
        }
        s16x4 gf;
        for (int r = 0; r < 4; r++) gf[r] = (short)f2bf_fast(gacc[r]);

        // out = pred + G @ errS
        f32x4 o0 = mfma16(gf, es0, acc0);
        f32x4 o1 = mfma16(gf, es1, acc1);

        // W update: W += k^T @ errS
        for (int mt = 0; mt < 8; mt++) {
            W[mt][0] = mfma16(ktf[mt], es0, W[mt][0]);
            W[mt][1] = mfma16(ktf[mt], es1, W[mt][1]);
        }

        // store out chunk (fire-and-forget)
        for (int r = 0; r < 4; r++) {
            obase[(size_t)(s0 + 4 * q + r) * 2048 + l15]      = f2bf_fast(o0[r]);
            obase[(size_t)(s0 + 4 * q + r) * 2048 + 16 + l15] = f2bf_fast(o1[r]);
        }

        __builtin_amdgcn_wave_barrier();   // wb reads done before shadow rewrite
        for (int mt = 0; mt < 8; mt++)
            for (int nt = 0; nt < 2; nt++) {
                uint32_t p0 = (uint32_t)f2bf_fast(W[mt][nt][0]) | ((uint32_t)f2bf_fast(W[mt][nt][1]) << 16);
                uint32_t p1 = (uint32_t)f2bf_fast(W[mt][nt][2]) | ((uint32_t)f2bf_fast(W[mt][nt][3]) << 16);
                int e = 16 * nt + l15, d = 16 * mt + 4 * q;
                u32x2 pp; pp[0] = p0; pp[1] = p1;
                *(u32x2*)(wb + e * 136 + d) = pp;
            }
        __builtin_amdgcn_wave_barrier();   // shadow visible before next pred
    }
}

// ---------------------------------------------------------------------------
// LayerNorm over rows of 2048 (biased var), * g + b; X bf16, g/b fp32, Y bf16
// ---------------------------------------------------------------------------
__global__ __launch_bounds__(256) void ln_kernel(
    const uint16_t* __restrict__ X, const float* __restrict__ Gm,
    const float* __restrict__ Bt, uint16_t* __restrict__ Y)
{
    const int row = blockIdx.x, t = threadIdx.x;
    const uint16_t* xr = X + (size_t)row * 2048 + t * 8;
    u32x4 raw = *(const u32x4*)xr;
    const uint16_t* pr = (const uint16_t*)&raw;
    float v[8];
    float s = 0.f, s2 = 0.f;
    for (int i = 0; i < 8; i++) {
        v[i] = bf2f(pr[i]);
        s += v[i];
        s2 += v[i] * v[i];
    }
    for (int off = 32; off; off >>= 1) {
        s  += __shfl_down(s, off, 64);
        s2 += __shfl_down(s2, off, 64);
    }
    __shared__ float red[8];
    if ((t & 63) == 0) { red[(t >> 6) * 2] = s; red[(t >> 6) * 2 + 1] = s2; }
    __syncthreads();
    float ts  = red[0] + red[2] + red[4] + red[6];
    float ts2 = red[1] + red[3] + red[5] + red[7];
    float mu  = ts * (1.0f / 2048.0f);
    float var = ts2 * (1.0f / 2048.0f) - mu * mu;
    float inv = rsqrtf(var + 1e-5f);
    uint16_t outv[8];
    for (int i = 0; i < 8; i++) {
        float y = (v[i] - mu) * inv * Gm[t * 8 + i] + Bt[t * 8 + i];
        outv[i] = f2bf(y);
    }
    u32x4 ov;
    __builtin_memcpy(&ov, outv, 16);
    *(u32x4*)(Y + (size_t)row * 2048 + t * 8) = ov;
}

// ---------------------------------------------------------------------------
extern "C" void kernel_launch(void* const* d_in, const int* in_sizes, int n_in,
                              void* d_out, int out_size, void* d_ws, size_t ws_size,
                              hipStream_t stream)
{
    const float* x  = (const float*)d_in[0];
    const float* Wk = (const float*)d_in[1];
    const float* Wv = (const float*)d_in[2];
    const float* Wo = (const float*)d_in[3];
    const float* lg = (const float*)d_in[4];
    const float* lb = (const float*)d_in[5];
    const float* W0 = (const float*)d_in[6];
    float* out = (float*)d_out;

    const size_t NTOK = 8192, HID = 2048;
    // ws (bf16 elems): xb(->kp after GEMMs) | wbuf | kb | vb | kt | vt  ~176 MB
    uint16_t* xb   = (uint16_t*)d_ws;          // 8192*2048; reused as kp
    uint16_t* wbuf = xb + NTOK * HID;          // 2048*2048
    uint16_t* kb   = wbuf + HID * HID;         // 8192*2048
    uint16_t* vb   = kb + NTOK * HID;          // 8192*2048
    uint16_t* kt   = vb + NTOK * HID;          // 8192*2048
    uint16_t* vt   = kt + NTOK * HID;          // 8192*2048
    uint16_t* kp   = xb;                       // xb dead after both proj GEMMs
    uint16_t* ob   = (uint16_t*)d_out;         // scan out parks in d_out bytes
    uint16_t* lnb  = kb;                       // kb dead after repack

    dim3 grid(16, 64), blk(256);
    const int nX4 = (int)(NTOK * HID / 4), nW4 = (int)(HID * HID / 4);

    cvt_bf16<<<4096, 256, 0, stream>>>(x, xb, nX4);
    cvt_bf16<<<4096, 256, 0, stream>>>(Wk, wbuf, nW4);
    gemm_bt<false><<<grid, blk, 0, stream>>>(xb, wbuf, kb, nullptr, 8192, 2048, 2048);
    cvt_bf16<<<4096, 256, 0, stream>>>(Wv, wbuf, nW4);
    gemm_bt<false><<<grid, blk, 0, stream>>>(xb, wbuf, vb, nullptr, 8192, 2048, 2048);
    repack<<<8192, 64, 0, stream>>>(kb, vb, kp, kt, vt);
    ttt_scan<<<256, 64, 0, stream>>>(kp, kt, vt, W0, ob);
    ln_kernel<<<8192, 256, 0, stream>>>(ob, lg, lb, lnb);
    cvt_bf16<<<4096, 256, 0, stream>>>(Wo, wbuf, nW4);
    gemm_bt<true><<<grid, blk, 0, stream>>>(lnb, wbuf, out, x, 8192, 2048, 2048);
}

// Round 5
// 711.468 us; speedup vs baseline: 1.1058x; 1.0469x over previous
//
#include <hip/hip_runtime.h>
#include <cstdint>
#include <cstddef>

typedef __attribute__((ext_vector_type(4))) float    f32x4;
typedef __attribute__((ext_vector_type(8))) __bf16   bf16x8;
typedef __attribute__((ext_vector_type(4))) short    s16x4;
typedef __attribute__((ext_vector_type(4))) uint32_t u32x4;
typedef __attribute__((ext_vector_type(2))) uint32_t u32x2;

__device__ __forceinline__ float bf2f(uint16_t h) {
    uint32_t u = ((uint32_t)h) << 16;
    return __builtin_bit_cast(float, u);
}
__device__ __forceinline__ uint16_t f2bf(float f) {
    uint32_t u = __builtin_bit_cast(uint32_t, f);
    uint32_t r = (u + 0x7fffu + ((u >> 16) & 1u)) >> 16;  // RNE
    return (uint16_t)r;
}
// native HW convert (RNE) — for hot loops
__device__ __forceinline__ uint16_t f2bf_fast(float f) {
    __bf16 h = (__bf16)f;
    return __builtin_bit_cast(uint16_t, h);
}

__device__ __forceinline__ f32x4 mfma32(bf16x8 a, bf16x8 b, f32x4 c) {
    return __builtin_amdgcn_mfma_f32_16x16x32_bf16(a, b, c, 0, 0, 0);
}
__device__ __forceinline__ f32x4 mfma16(s16x4 a, s16x4 b, f32x4 c) {
    return __builtin_amdgcn_mfma_f32_16x16x16bf16_1k(a, b, c, 0, 0, 0);
}

// async global->LDS, 16B per lane (GEMM staging)
__device__ __forceinline__ void gload16(const void* g, void* l) {
    __builtin_amdgcn_global_load_lds(
        (const __attribute__((address_space(1))) uint32_t*)g,
        (__attribute__((address_space(3))) uint32_t*)l, 16, 0, 0);
}

// barrier WITHOUT vmcnt drain: LDS ops drained, global loads/stores stay in flight
__device__ __forceinline__ void lds_barrier() {
    asm volatile("s_waitcnt lgkmcnt(0)\n\ts_barrier" ::: "memory");
}

// ---------------------------------------------------------------------------
// fp32 -> bf16 elementwise, 4 elems/thread/iter, grid-stride
// ---------------------------------------------------------------------------
__global__ __launch_bounds__(256) void cvt_bf16(
    const float* __restrict__ s, uint16_t* __restrict__ d, int n4)
{
    int i = blockIdx.x * 256 + threadIdx.x;
    const int stride = gridDim.x * 256;
    for (; i < n4; i += stride) {
        f32x4 v = ((const f32x4*)s)[i];
        u32x2 p;
        p[0] = (uint32_t)f2bf(v[0]) | ((uint32_t)f2bf(v[1]) << 16);
        p[1] = (uint32_t)f2bf(v[2]) | ((uint32_t)f2bf(v[3]) << 16);
        ((u32x2*)d)[i] = p;
    }
}

// ---------------------------------------------------------------------------
// C[M,N] = A[M,K] @ B[N,K]^T, bf16 in, fp32 acc.  (m97 structure)
// ---------------------------------------------------------------------------
template <bool F32OUT>
__global__ __launch_bounds__(256) void gemm_bt(
    const uint16_t* __restrict__ A, const uint16_t* __restrict__ B,
    void* __restrict__ Cv, const float* __restrict__ R,
    int M, int N, int K)
{
    __shared__ __align__(16) uint16_t lA[128 * 32];
    __shared__ __align__(16) uint16_t lB[128 * 32];
    const int tid = threadIdx.x;
    const int wv = tid >> 6, ln = tid & 63;
    const int l15 = ln & 15, q = ln >> 4;
    const int m0 = blockIdx.y * 128, n0 = blockIdx.x * 128;
    const int wm = (wv >> 1) * 64, wn = (wv & 1) * 64;

    const uint16_t* ga = A + (size_t)(m0 + wv * 32 + (ln >> 2)) * K + (ln & 3) * 8;
    const uint16_t* gb = B + (size_t)(n0 + wv * 32 + (ln >> 2)) * K + (ln & 3) * 8;
    uint16_t* la = lA + (wv * 32) * 32;
    uint16_t* lb = lB + (wv * 32) * 32;

    f32x4 acc[4][4];
    for (int i = 0; i < 4; i++)
        for (int j = 0; j < 4; j++)
            acc[i][j] = (f32x4){0.f, 0.f, 0.f, 0.f};

    for (int kt = 0; kt < K; kt += 32) {
        gload16(ga + kt, la);
        gload16(ga + (size_t)16 * K + kt, la + 16 * 32);
        gload16(gb + kt, lb);
        gload16(gb + (size_t)16 * K + kt, lb + 16 * 32);
        __syncthreads();

        bf16x8 af[4], bfv[4];
        for (int mt = 0; mt < 4; mt++)
            af[mt] = __builtin_bit_cast(bf16x8,
                *(const u32x4*)(lA + (wm + mt * 16 + l15) * 32 + q * 8));
        for (int nt = 0; nt < 4; nt++)
            bfv[nt] = __builtin_bit_cast(bf16x8,
                *(const u32x4*)(lB + (wn + nt * 16 + l15) * 32 + q * 8));
        for (int mt = 0; mt < 4; mt++)
            for (int nt = 0; nt < 4; nt++)
                acc[mt][nt] = mfma32(af[mt], bfv[nt], acc[mt][nt]);
        __syncthreads();
    }

    for (int mt = 0; mt < 4; mt++)
        for (int nt = 0; nt < 4; nt++)
            for (int r = 0; r < 4; r++) {
                int row = m0 + wm + mt * 16 + q * 4 + r;
                int col = n0 + wn + nt * 16 + l15;
                size_t idx = (size_t)row * N + col;
                float v = acc[mt][nt][r];
                if (F32OUT) {
                    ((float*)Cv)[idx] = v + R[idx];
                } else {
                    ((uint16_t*)Cv)[idx] = f2bf(v);
                }
            }
}

// ---------------------------------------------------------------------------
// repack + fused RoPE: per (b,h,c) emit contiguous tiles
//   kp[g][m16][d128], kt[g][d128][m16], vt[g][e128][m16];  g=((b*16)+h)*128+c
// ---------------------------------------------------------------------------
__global__ __launch_bounds__(64) void repack(
    const uint16_t* __restrict__ kb, const uint16_t* __restrict__ vb,
    uint16_t* __restrict__ kp, uint16_t* __restrict__ kt,
    uint16_t* __restrict__ vt)
{
    const int g = blockIdx.x;
    const int c = g & 127, h = (g >> 7) & 15, b = g >> 11;
    const int ln = threadIdx.x;
    const int m = ln >> 2, cb = (ln & 3) * 32;
    const size_t tok = (size_t)b * 2048 + c * 16 + m;
    const int s = c * 16 + m;
    const uint16_t* krow = kb + tok * 2048 + h * 128;
    const uint16_t* vrow = vb + tok * 2048 + h * 128;

    u32x4 kraw[4], praw[4], vraw[4];
    for (int i = 0; i < 4; i++) {
        kraw[i] = *(const u32x4*)(krow + cb + 8 * i);
        praw[i] = *(const u32x4*)(krow + (cb ^ 64) + 8 * i);
        vraw[i] = *(const u32x4*)(vrow + cb + 8 * i);
    }
    const uint16_t* ku = (const uint16_t*)kraw;
    const uint16_t* pu = (const uint16_t*)praw;
    const uint16_t* vu = (const uint16_t*)vraw;

    uint16_t ko[32];
    for (int j = 0; j < 32; j++) {
        int col = cb + j;
        int p = col & 63;
        float invf = exp2f((float)p * (-13.287712379549449f / 64.0f));
        float a = (float)s * invf;
        float sn, cs;
        __sincosf(a, &sn, &cs);
        float u1 = bf2f(ku[j]), u2 = bf2f(pu[j]);
        float o = (col < 64) ? (u1 * cs - u2 * sn) : (u1 * cs + u2 * sn);
        ko[j] = f2bf(o);
    }

    uint16_t* kpg = kp + (size_t)g * 2048;
    uint16_t* ktg = kt + (size_t)g * 2048;
    uint16_t* vtg = vt + (size_t)g * 2048;
    for (int i = 0; i < 4; i++) {
        u32x4 pk;
        uint32_t* pw = (uint32_t*)&pk;
        for (int w = 0; w < 4; w++)
            pw[w] = (uint32_t)ko[8 * i + 2 * w] | ((uint32_t)ko[8 * i + 2 * w + 1] << 16);
        *(u32x4*)(kpg + m * 128 + cb + 8 * i) = pk;
    }
    for (int j = 0; j < 32; j++) {
        ktg[(cb + j) * 16 + m] = ko[j];
        vtg[(cb + j) * 16 + m] = vu[j];
    }
}

// ---------------------------------------------------------------------------
// TTT scan: one 256-thread WG per (b,h); wave wv owns e-slice [32*wv, 32*wv+32).
// Cooperative staging: each wave loads 1/4 of kp/kt/vt tile (3 u32x4 regs —
// tiny, unspillable), double-buffered LDS slots, lds_barrier (no vmcnt drain).
// W master fp32 in registers; bf16 shadow per-wave in LDS [e][d].
// pred = k@W; G = k k^T; errS = (v-pred)/1024; W += k^T@errS; out = pred+G@errS.
// ---------------------------------------------------------------------------
__global__ __launch_bounds__(256, 1) void ttt_scan(
    const uint16_t* __restrict__ kp, const uint16_t* __restrict__ kt,
    const uint16_t* __restrict__ vt, const float* __restrict__ W0,
    uint16_t* __restrict__ O)
{
    __shared__ __align__(16) uint16_t kbuf[2][16 * 136];   // [m][d] +8 pad
    __shared__ __align__(16) uint16_t ktb[2][128 * 24];    // [d][m] +8 pad
    __shared__ __align__(16) uint16_t vtb[2][128 * 24];    // [e][m] +8 pad
    __shared__ __align__(16) uint16_t wb[4][32 * 136];     // per-wave [e][d] +8 pad

    const int g = blockIdx.x;              // b*16 + h
    const int h = g & 15, b = g >> 4;
    const int tid = threadIdx.x;
    const int wv = tid >> 6, ln = tid & 63;
    const int e0 = wv * 32;
    const int l15 = ln & 15, q = ln >> 4;
    uint16_t* wbp = wb[wv];

    // W[mt][nt] reg r holds W[d = 16mt+4q+r][e = e0+16nt+l15]  (fp32 master)
    f32x4 W[8][2];
    {
        const float* w0p = W0 + (size_t)g * 128 * 128;
        for (int mt = 0; mt < 8; mt++)
            for (int nt = 0; nt < 2; nt++)
                for (int r = 0; r < 4; r++)
                    W[mt][nt][r] = w0p[(size_t)(16 * mt + 4 * q + r) * 128
                                       + e0 + 16 * nt + l15];
    }
    for (int mt = 0; mt < 8; mt++)
        for (int nt = 0; nt < 2; nt++) {
            uint32_t p0 = (uint32_t)f2bf_fast(W[mt][nt][0]) | ((uint32_t)f2bf_fast(W[mt][nt][1]) << 16);
            uint32_t p1 = (uint32_t)f2bf_fast(W[mt][nt][2]) | ((uint32_t)f2bf_fast(W[mt][nt][3]) << 16);
            int e = 16 * nt + l15, d = 16 * mt + 4 * q;
            u32x2 pp; pp[0] = p0; pp[1] = p1;
            *(u32x2*)(wbp + e * 136 + d) = pp;
        }
    __builtin_amdgcn_wave_barrier();

    const uint16_t* kpw = kp + (size_t)g * 128 * 2048;
    const uint16_t* ktw = kt + (size_t)g * 128 * 2048;
    const uint16_t* vtw = vt + (size_t)g * 128 * 2048;
    uint16_t*     obase = O  + (size_t)b * 2048 * 2048 + h * 128 + e0;

    // per-wave quarter-tile prefetch registers (12 VGPRs total)
    u32x4 rk, rt, rv;
    const int kofs = wv * 512 + (ln >> 4) * 128 + (ln & 15) * 8;  // kp quarter
    const int tofs = wv * 512 + (ln >> 1) * 16 + (ln & 1) * 8;    // kt/vt quarter
    auto load_regs = [&](int c) {
        rk = *(const u32x4*)(kpw + (size_t)c * 2048 + kofs);
        rt = *(const u32x4*)(ktw + (size_t)c * 2048 + tofs);
        rv = *(const u32x4*)(vtw + (size_t)c * 2048 + tofs);
    };
    auto stage = [&](int sl) {
        *(u32x4*)(kbuf[sl] + (4 * wv + (ln >> 4)) * 136 + (ln & 15) * 8) = rk;
        *(u32x4*)(ktb[sl] + (32 * wv + (ln >> 1)) * 24 + (ln & 1) * 8) = rt;
        *(u32x4*)(vtb[sl] + (32 * wv + (ln >> 1)) * 24 + (ln & 1) * 8) = rv;
    };

    load_regs(0);
    stage(0);
    load_regs(1);
    lds_barrier();

    for (int c = 0; c < 128; c++) {
        const int s0 = c * 16;
        const int sl = c & 1;

        // fragments from slot sl
        bf16x8 af[4];
        for (int ks = 0; ks < 4; ks++)
            af[ks] = __builtin_bit_cast(bf16x8,
                *(const u32x4*)(kbuf[sl] + l15 * 136 + ks * 32 + q * 8));
        s16x4 ktf[8];
        for (int mt = 0; mt < 8; mt++)
            ktf[mt] = *(const s16x4*)(ktb[sl] + (16 * mt + l15) * 24 + 4 * q);
        s16x4 vv0 = *(const s16x4*)(vtb[sl] + (e0 + l15) * 24 + 4 * q);
        s16x4 vv1 = *(const s16x4*)(vtb[sl] + (e0 + 16 + l15) * 24 + 4 * q);

        // stage next step's tile (regs loaded one full step ago), refill regs
        if (c < 127) stage(sl ^ 1);
        if (c < 126) load_regs(c + 2);

        // pred (2 n-tiles) and G = k k^T
        f32x4 acc0 = (f32x4){0.f, 0.f, 0.f, 0.f};
        f32x4 acc1 = (f32x4){0.f, 0.f, 0.f, 0.f};
        f32x4 gacc = (f32x4){0.f, 0.f, 0.f, 0.f};
        for (int ks = 0; ks < 4; ks++) {
            bf16x8 b0 = __builtin_bit_cast(bf16x8,
                *(const u32x4*)(wbp + (l15) * 136 + ks * 32 + q * 8));
            bf16x8 b1 = __builtin_bit_cast(bf16x8,
                *(const u32x4*)(wbp + (16 + l15) * 136 + ks * 32 + q * 8));
            acc0 = mfma32(af[ks], b0, acc0);
            acc1 = mfma32(af[ks], b1, acc1);
            gacc = mfma32(af[ks], af[ks], gacc);
        }

        // errS = (v - pred)/1024, already in 16x16x16 A/B operand layout
        s16x4 es0, es1;
        for (int r = 0; r < 4; r++) {
            es0[r] = (short)f2bf_fast((bf2f((uint16_t)vv0[r]) - acc0[r]) * (1.0f / 1024.0f));
            es1[r] = (short)f2bf_fast((bf2f((uint16_t)vv1[r]) - acc1[r]) * (1.0f / 1024.0f));
        }
        s16x4 gf;
        for (int r = 0; r < 4; r++) gf[r] = (short)f2bf_fast(gacc[r]);

        // out = pred + G @ errS
        f32x4 o0 = mfma16(gf, es0, acc0);
        f32x4 o1 = mfma16(gf, es1, acc1);

        // W update: W += k^T @ errS
        for (int mt = 0; mt < 8; mt++) {
            W[mt][0] = mfma16(ktf[mt], es0, W[mt][0]);
            W[mt][1] = mfma16(ktf[mt], es1, W[mt][1]);
        }

        // store out chunk (fire-and-forget; never drained by lds_barrier)
        for (int r = 0; r < 4; r++) {
            obase[(size_t)(s0 + 4 * q + r) * 2048 + l15]      = f2bf_fast(o0[r]);
            obase[(size_t)(s0 + 4 * q + r) * 2048 + 16 + l15] = f2bf_fast(o1[r]);
        }

        __builtin_amdgcn_wave_barrier();   // wbp reads done before shadow rewrite
        for (int mt = 0; mt < 8; mt++)
            for (int nt = 0; nt < 2; nt++) {
                uint32_t p0 = (uint32_t)f2bf_fast(W[mt][nt][0]) | ((uint32_t)f2bf_fast(W[mt][nt][1]) << 16);
                uint32_t p1 = (uint32_t)f2bf_fast(W[mt][nt][2]) | ((uint32_t)f2bf_fast(W[mt][nt][3]) << 16);
                int e = 16 * nt + l15, d = 16 * mt + 4 * q;
                u32x2 pp; pp[0] = p0; pp[1] = p1;
                *(u32x2*)(wbp + e * 136 + d) = pp;
            }

        lds_barrier();   // staging visible to all; slot sl free for overwrite
    }
}

// ---------------------------------------------------------------------------
// LayerNorm over rows of 2048 (biased var), * g + b; X bf16, g/b fp32, Y bf16
// ---------------------------------------------------------------------------
__global__ __launch_bounds__(256) void ln_kernel(
    const uint16_t* __restrict__ X, const float* __restrict__ Gm,
    const float* __restrict__ Bt, uint16_t* __restrict__ Y)
{
    const int row = blockIdx.x, t = threadIdx.x;
    const uint16_t* xr = X + (size_t)row * 2048 + t * 8;
    u32x4 raw = *(const u32x4*)xr;
    const uint16_t* pr = (const uint16_t*)&raw;
    float v[8];
    float s = 0.f, s2 = 0.f;
    for (int i = 0; i < 8; i++) {
        v[i] = bf2f(pr[i]);
        s += v[i];
        s2 += v[i] * v[i];
    }
    for (int off = 32; off; off >>= 1) {
        s  += __shfl_down(s, off, 64);
        s2 += __shfl_down(s2, off, 64);
    }
    __shared__ float red[8];
    if ((t & 63) == 0) { red[(t >> 6) * 2] = s; red[(t >> 6) * 2 + 1] = s2; }
    __syncthreads();
    float ts  = red[0] + red[2] + red[4] + red[6];
    float ts2 = red[1] + red[3] + red[5] + red[7];
    float mu  = ts * (1.0f / 2048.0f);
    float var = ts2 * (1.0f / 2048.0f) - mu * mu;
    float inv = rsqrtf(var + 1e-5f);
    uint16_t outv[8];
    for (int i = 0; i < 8; i++) {
        float y = (v[i] - mu) * inv * Gm[t * 8 + i] + Bt[t * 8 + i];
        outv[i] = f2bf(y);
    }
    u32x4 ov;
    __builtin_memcpy(&ov, outv, 16);
    *(u32x4*)(Y + (size_t)row * 2048 + t * 8) = ov;
}

// ---------------------------------------------------------------------------
extern "C" void kernel_launch(void* const* d_in, const int* in_sizes, int n_in,
                              void* d_out, int out_size, void* d_ws, size_t ws_size,
                              hipStream_t stream)
{
    const float* x  = (const float*)d_in[0];
    const float* Wk = (const float*)d_in[1];
    const float* Wv = (const float*)d_in[2];
    const float* Wo = (const float*)d_in[3];
    const float* lg = (const float*)d_in[4];
    const float* lb = (const float*)d_in[5];
    const float* W0 = (const float*)d_in[6];
    float* out = (float*)d_out;

    const size_t NTOK = 8192, HID = 2048;
    // ws (bf16 elems): xb(->kp after GEMMs) | wbuf | kb | vb | kt | vt  ~176 MB
    uint16_t* xb   = (uint16_t*)d_ws;          // 8192*2048; reused as kp
    uint16_t* wbuf = xb + NTOK * HID;          // 2048*2048
    uint16_t* kb   = wbuf + HID * HID;         // 8192*2048
    uint16_t* vb   = kb + NTOK * HID;          // 8192*2048
    uint16_t* kt   = vb + NTOK * HID;          // 8192*2048
    uint16_t* vt   = kt + NTOK * HID;          // 8192*2048
    uint16_t* kp   = xb;                       // xb dead after both proj GEMMs
    uint16_t* ob   = (uint16_t*)d_out;         // scan out parks in d_out bytes
    uint16_t* lnb  = kb;                       // kb dead after repack

    dim3 grid(16, 64), blk(256);
    const int nX4 = (int)(NTOK * HID / 4), nW4 = (int)(HID * HID / 4);

    cvt_bf16<<<4096, 256, 0, stream>>>(x, xb, nX4);
    cvt_bf16<<<4096, 256, 0, stream>>>(Wk, wbuf, nW4);
    gemm_bt<false><<<grid, blk, 0, stream>>>(xb, wbuf, kb, nullptr, 8192, 2048, 2048);
    cvt_bf16<<<4096, 256, 0, stream>>>(Wv, wbuf, nW4);
    gemm_bt<false><<<grid, blk, 0, stream>>>(xb, wbuf, vb, nullptr, 8192, 2048, 2048);
    repack<<<8192, 64, 0, stream>>>(kb, vb, kp, kt, vt);
    ttt_scan<<<64, 256, 0, stream>>>(kp, kt, vt, W0, ob);
    ln_kernel<<<8192, 256, 0, stream>>>(ob, lg, lb, lnb);
    cvt_bf16<<<4096, 256, 0, stream>>>(Wo, wbuf, nW4);
    gemm_bt<true><<<grid, blk, 0, stream>>>(lnb, wbuf, out, x, 8192, 2048, 2048);
}